// Round 1
// baseline (240.795 us; speedup 1.0000x reference)
//
#include <hip/hip_runtime.h>
#include <stdint.h>

#define D 4096
#define RANK 8
#define ALPHA 1.5f
#define BETA 0.5f
#define SUM_TIMESTEPS 28000
#define K_TOP 64

// ws layout (bytes):
//   0..31 : u32 hdr[8]: [0]=maxbits1 [1]=maxbits2 [2]=cnt1 [3]=cnt2 [4]=flag
//   256   : float t[rows*RANK]   (256 KB for rows=8192)
//   then  : cand0[cap], cand1[cap]
#define WS_T_OFF 256

__global__ void k_init(unsigned* __restrict__ hdr) {
    if (threadIdx.x < 8) hdr[threadIdx.x] = 0u;
}

__device__ __forceinline__ float dot4(float4 a, float4 b) {
    return fmaf(a.x, b.x, fmaf(a.y, b.y, fmaf(a.z, b.z, a.w * b.w)));
}

// ---------------------------------------------------------------------------
// Pass 1: global max of |wa@wb| per matrix.
// grid: (4 i-tiles * 64 o-chunks, 2 matrices), block 256.
// Each thread holds wb fragment (4 i x 8 r = 32 regs), loops 64 rows of wa.
// ---------------------------------------------------------------------------
__global__ __launch_bounds__(256) void k_pass_max(
    const float* __restrict__ wa1, const float* __restrict__ wb1,
    const float* __restrict__ wa2, const float* __restrict__ wb2,
    unsigned* __restrict__ hdr) {
    const int tid = threadIdx.x;
    const int mat = blockIdx.y;
    const float* __restrict__ wa = mat ? wa2 : wa1;
    const float* __restrict__ wb = mat ? wb2 : wb1;
    const int i0 = (blockIdx.x & 3) * 1024 + tid * 4;
    const int obase = (blockIdx.x >> 2) * 64;

    float4 wbv[RANK];
#pragma unroll
    for (int r = 0; r < RANK; ++r)
        wbv[r] = *(const float4*)(wb + r * D + i0);

    float vmax = 0.f;
#pragma unroll 4
    for (int oo = 0; oo < 64; ++oo) {
        const float* __restrict__ war = wa + (size_t)(obase + oo) * RANK;
        float4 s = make_float4(0.f, 0.f, 0.f, 0.f);
#pragma unroll
        for (int r = 0; r < RANK; ++r) {
            const float a = war[r];
            s.x = fmaf(a, wbv[r].x, s.x);
            s.y = fmaf(a, wbv[r].y, s.y);
            s.z = fmaf(a, wbv[r].z, s.z);
            s.w = fmaf(a, wbv[r].w, s.w);
        }
        vmax = fmaxf(vmax, fmaxf(fmaxf(fabsf(s.x), fabsf(s.y)),
                                 fmaxf(fabsf(s.z), fabsf(s.w))));
    }
    // wave reduce then cross-wave
    for (int off = 32; off; off >>= 1)
        vmax = fmaxf(vmax, __shfl_xor(vmax, off, 64));
    __shared__ float smax[4];
    const int wave = tid >> 6, lane = tid & 63;
    if (lane == 0) smax[wave] = vmax;
    __syncthreads();
    if (tid == 0) {
        float m = fmaxf(fmaxf(smax[0], smax[1]), fmaxf(smax[2], smax[3]));
        atomicMax(&hdr[mat], __float_as_uint(m));  // positive floats: bit-order == value-order
    }
}

// ---------------------------------------------------------------------------
// Pass 2: collect all |elem| >= 0.5*max into candidate buffer.
// LDS-buffered appends; one global atomicAdd per block (avoids hot counter).
// ---------------------------------------------------------------------------
__global__ __launch_bounds__(256) void k_pass_collect(
    const float* __restrict__ wa1, const float* __restrict__ wb1,
    const float* __restrict__ wa2, const float* __restrict__ wb2,
    unsigned* __restrict__ hdr,
    float* __restrict__ cand0, float* __restrict__ cand1, unsigned cap) {
    __shared__ float lbuf[4096];
    __shared__ unsigned lcnt;
    __shared__ unsigned gbase;
    const int tid = threadIdx.x;
    const int mat = blockIdx.y;
    if (tid == 0) lcnt = 0u;
    __syncthreads();

    const float* __restrict__ wa = mat ? wa2 : wa1;
    const float* __restrict__ wb = mat ? wb2 : wb1;
    float* __restrict__ cand = mat ? cand1 : cand0;
    const float T = 0.5f * __uint_as_float(hdr[mat]);
    const int i0 = (blockIdx.x & 3) * 1024 + tid * 4;
    const int obase = (blockIdx.x >> 2) * 64;

    float4 wbv[RANK];
#pragma unroll
    for (int r = 0; r < RANK; ++r)
        wbv[r] = *(const float4*)(wb + r * D + i0);

#pragma unroll 2
    for (int oo = 0; oo < 64; ++oo) {
        const float* __restrict__ war = wa + (size_t)(obase + oo) * RANK;
        float4 s = make_float4(0.f, 0.f, 0.f, 0.f);
#pragma unroll
        for (int r = 0; r < RANK; ++r) {
            const float a = war[r];
            s.x = fmaf(a, wbv[r].x, s.x);
            s.y = fmaf(a, wbv[r].y, s.y);
            s.z = fmaf(a, wbv[r].z, s.z);
            s.w = fmaf(a, wbv[r].w, s.w);
        }
        const float av[4] = {fabsf(s.x), fabsf(s.y), fabsf(s.z), fabsf(s.w)};
#pragma unroll
        for (int j = 0; j < 4; ++j) {
            if (av[j] >= T) {
                unsigned li = atomicAdd(&lcnt, 1u);
                if (li < 4096u) lbuf[li] = av[j];
            }
        }
    }
    __syncthreads();
    unsigned n = lcnt < 4096u ? lcnt : 4096u;
    if (tid == 0) gbase = atomicAdd(&hdr[2 + mat], n);
    __syncthreads();
    for (unsigned j = tid; j < n; j += 256u) {
        unsigned gi = gbase + j;
        if (gi < cap) cand[gi] = lbuf[j];
    }
}

// ---------------------------------------------------------------------------
// Pass 3: single block. Histogram candidates on float bits (1025 bins spanning
// [0.5*max, max]); scan top-down for exact-ish top-64 sum; write flag.
// ---------------------------------------------------------------------------
__global__ __launch_bounds__(256) void k_select(
    unsigned* __restrict__ hdr,
    const float* __restrict__ cand0, const float* __restrict__ cand1,
    unsigned cap, const int* __restrict__ tsp) {
    __shared__ unsigned hcnt[1025];
    __shared__ float hsum[1025];
    __shared__ float ssum[2];

    for (int mat = 0; mat < 2; ++mat) {
        for (int b = threadIdx.x; b < 1025; b += 256) { hcnt[b] = 0u; hsum[b] = 0.f; }
        __syncthreads();
        const unsigned bitsT = __float_as_uint(0.5f * __uint_as_float(hdr[mat]));
        unsigned n = hdr[2 + mat];
        if (n > cap) n = cap;
        const float* __restrict__ cand = mat ? cand1 : cand0;
        for (unsigned j = threadIdx.x; j < n; j += 256u) {
            float v = cand[j];
            unsigned k = (__float_as_uint(v) - bitsT) >> 13;
            if (k > 1024u) k = 1024u;
            atomicAdd(&hcnt[k], 1u);
            atomicAdd(&hsum[k], v);
        }
        __syncthreads();
        if (threadIdx.x == 0) {
            float s = 0.f;
            unsigned c = 0;
            for (int b = 1024; b >= 0; --b) {
                unsigned hc = hcnt[b];
                if (!hc) continue;
                if (c + hc <= K_TOP) {
                    s += hsum[b];
                    c += hc;
                    if (c == K_TOP) break;
                } else {
                    unsigned need = K_TOP - c;
                    s += hsum[b] * ((float)need / (float)hc);  // bin width 2^-10 rel: negligible error
                    break;
                }
            }
            ssum[mat] = s;
        }
        __syncthreads();
    }
    if (threadIdx.x == 0) {
        const int tr = (*tsp) % SUM_TIMESTEPS;
        const float scale = fmodf(ALPHA * (float)tr / (float)SUM_TIMESTEPS + BETA, ALPHA);
        const float temp_ratio = ssum[0] / (ssum[1] * scale);  // AVG_RATIO = 1.0
        hdr[4] = (temp_ratio > 1.0f) ? 1u : 0u;                // 1 -> matrix1
    }
}

// ---------------------------------------------------------------------------
// Kernel T: t[m, r] = sum_i h[m,i] * wb[r,i].   HBM-bound: streams h (128 MiB).
// Block = 4 waves; each wave owns 2 rows; lane owns 4 i's per k-slice.
// ---------------------------------------------------------------------------
__global__ __launch_bounds__(256) void k_t(
    const float* __restrict__ h, const float* __restrict__ wb1,
    const float* __restrict__ wb2, const unsigned* __restrict__ hdr,
    float* __restrict__ t) {
    const int tid = threadIdx.x;
    const int wave = tid >> 6, lane = tid & 63;
    const float* __restrict__ wb = hdr[4] ? wb1 : wb2;
    const int m0 = blockIdx.x * 8 + wave * 2;

    float acc[2][RANK];
#pragma unroll
    for (int row = 0; row < 2; ++row)
#pragma unroll
        for (int r = 0; r < RANK; ++r) acc[row][r] = 0.f;

    for (int k = 0; k < 16; ++k) {
        const int i = k * 256 + lane * 4;
        float4 wbv[RANK];
#pragma unroll
        for (int r = 0; r < RANK; ++r)
            wbv[r] = *(const float4*)(wb + r * D + i);
#pragma unroll
        for (int row = 0; row < 2; ++row) {
            const float4 hv = *(const float4*)(h + (size_t)(m0 + row) * D + i);
#pragma unroll
            for (int r = 0; r < RANK; ++r)
                acc[row][r] = fmaf(hv.x, wbv[r].x,
                              fmaf(hv.y, wbv[r].y,
                              fmaf(hv.z, wbv[r].z,
                              fmaf(hv.w, wbv[r].w, acc[row][r]))));
        }
    }
#pragma unroll
    for (int row = 0; row < 2; ++row)
#pragma unroll
        for (int r = 0; r < RANK; ++r)
            for (int off = 32; off; off >>= 1)
                acc[row][r] += __shfl_xor(acc[row][r], off, 64);
    if (lane == 0) {
#pragma unroll
        for (int row = 0; row < 2; ++row)
#pragma unroll
            for (int r = 0; r < RANK; ++r)
                t[(size_t)(m0 + row) * RANK + r] = acc[row][r];
    }
}

// ---------------------------------------------------------------------------
// Kernel O: out[m, o] = sum_r t[m,r] * wa[o,r].  HBM-bound: streams out (128 MiB).
// Thread owns 4 o's (wa fragment in 32 regs), loops 16 rows.
// ---------------------------------------------------------------------------
__global__ __launch_bounds__(256) void k_o(
    const float* __restrict__ t, const float* __restrict__ wa1,
    const float* __restrict__ wa2, const unsigned* __restrict__ hdr,
    float* __restrict__ out) {
    const int tid = threadIdx.x;
    const float* __restrict__ wa = hdr[4] ? wa1 : wa2;
    const int o0 = (blockIdx.x & 3) * 1024 + tid * 4;
    const int m0 = (blockIdx.x >> 2) * 16;

    float4 A[8];  // A[2j+0]: (o0+j) r0..3, A[2j+1]: (o0+j) r4..7
#pragma unroll
    for (int j = 0; j < 8; ++j)
        A[j] = *(const float4*)(wa + (size_t)o0 * RANK + j * 4);

    for (int rr = 0; rr < 16; ++rr) {
        const int m = m0 + rr;
        const float4 t03 = *(const float4*)(t + (size_t)m * RANK);
        const float4 t47 = *(const float4*)(t + (size_t)m * RANK + 4);
        float4 ov;
        ov.x = dot4(A[0], t03) + dot4(A[1], t47);
        ov.y = dot4(A[2], t03) + dot4(A[3], t47);
        ov.z = dot4(A[4], t03) + dot4(A[5], t47);
        ov.w = dot4(A[6], t03) + dot4(A[7], t47);
        *(float4*)(out + (size_t)m * D + o0) = ov;
    }
}

extern "C" void kernel_launch(void* const* d_in, const int* in_sizes, int n_in,
                              void* d_out, int out_size, void* d_ws, size_t ws_size,
                              hipStream_t stream) {
    const float* h   = (const float*)d_in[0];
    const float* wa1 = (const float*)d_in[1];
    const float* wb1 = (const float*)d_in[2];
    const float* wa2 = (const float*)d_in[3];
    const float* wb2 = (const float*)d_in[4];
    const int*   ts  = (const int*)d_in[5];
    float* out = (float*)d_out;

    const int rows = in_sizes[0] / D;  // 8192

    unsigned* hdr = (unsigned*)d_ws;
    float* tbuf = (float*)((char*)d_ws + WS_T_OFF);
    const size_t candOff = WS_T_OFF + (size_t)rows * RANK * 4;
    size_t avail = (ws_size > candOff) ? (ws_size - candOff) : 0;
    size_t capz = avail / 8;  // two float buffers
    if (capz > (1u << 20)) capz = (1u << 20);
    unsigned cap = (unsigned)capz;
    float* cand0 = (float*)((char*)d_ws + candOff);
    float* cand1 = cand0 + cap;

    hipLaunchKernelGGL(k_init, dim3(1), dim3(64), 0, stream, hdr);
    hipLaunchKernelGGL(k_pass_max, dim3(256, 2), dim3(256), 0, stream,
                       wa1, wb1, wa2, wb2, hdr);
    hipLaunchKernelGGL(k_pass_collect, dim3(256, 2), dim3(256), 0, stream,
                       wa1, wb1, wa2, wb2, hdr, cand0, cand1, cap);
    hipLaunchKernelGGL(k_select, dim3(1), dim3(256), 0, stream,
                       hdr, cand0, cand1, cap, ts);
    hipLaunchKernelGGL(k_t, dim3(rows / 8), dim3(256), 0, stream,
                       h, wb1, wb2, hdr, tbuf);
    hipLaunchKernelGGL(k_o, dim3(4 * (rows / 16)), dim3(256), 0, stream,
                       tbuf, wa1, wa2, hdr, out);
}

// Round 2
// 138.724 us; speedup vs baseline: 1.7358x; 1.7358x over previous
//
#include <hip/hip_runtime.h>
#include <stdint.h>

#define D 4096
#define RANK 8
#define ALPHA 1.5f
#define BETA 0.5f
#define SUM_TIMESTEPS 28000
#define K_TOP 64
#define NBINS 1024

// ws layout (bytes):
//   [0, 256)        : u32 hdr[]: [0]=maxbits1 [1]=maxbits2 [4]=flag
//   [256, 256+8K)   : u32  gcnt[2][NBINS]
//   [256+8K, +16K)  : f32  gsum[2][NBINS]
//   [16640, ...)    : f32  t[rows*RANK]
#define WS_HCNT_OFF 256
#define WS_HSUM_OFF (256 + 2 * NBINS * 4)
#define WS_T_OFF    (256 + 4 * NBINS * 4)

__global__ __launch_bounds__(1024) void k_init(unsigned* __restrict__ w) {
    // zero hdr + both histograms: (256 + 16384)/4 = 4160 words
    for (int i = threadIdx.x; i < 4160; i += 1024) w[i] = 0u;
}

__device__ __forceinline__ float dot4(float4 a, float4 b) {
    return fmaf(a.x, b.x, fmaf(a.y, b.y, fmaf(a.z, b.z, a.w * b.w)));
}

// ---------------------------------------------------------------------------
// Pass 1: global max of |wa@wb| per matrix.
// grid: (4 i-tiles * 64 o-chunks, 2 matrices), block 256.
// ---------------------------------------------------------------------------
__global__ __launch_bounds__(256) void k_pass_max(
    const float* __restrict__ wa1, const float* __restrict__ wb1,
    const float* __restrict__ wa2, const float* __restrict__ wb2,
    unsigned* __restrict__ hdr) {
    const int tid = threadIdx.x;
    const int mat = blockIdx.y;
    const float* __restrict__ wa = mat ? wa2 : wa1;
    const float* __restrict__ wb = mat ? wb2 : wb1;
    const int i0 = (blockIdx.x & 3) * 1024 + tid * 4;
    const int obase = (blockIdx.x >> 2) * 64;

    float4 wbv[RANK];
#pragma unroll
    for (int r = 0; r < RANK; ++r)
        wbv[r] = *(const float4*)(wb + r * D + i0);

    float vmax = 0.f;
#pragma unroll 4
    for (int oo = 0; oo < 64; ++oo) {
        const float* __restrict__ war = wa + (size_t)(obase + oo) * RANK;
        float4 s = make_float4(0.f, 0.f, 0.f, 0.f);
#pragma unroll
        for (int r = 0; r < RANK; ++r) {
            const float a = war[r];
            s.x = fmaf(a, wbv[r].x, s.x);
            s.y = fmaf(a, wbv[r].y, s.y);
            s.z = fmaf(a, wbv[r].z, s.z);
            s.w = fmaf(a, wbv[r].w, s.w);
        }
        vmax = fmaxf(vmax, fmaxf(fmaxf(fabsf(s.x), fabsf(s.y)),
                                 fmaxf(fabsf(s.z), fabsf(s.w))));
    }
    for (int off = 32; off; off >>= 1)
        vmax = fmaxf(vmax, __shfl_xor(vmax, off, 64));
    __shared__ float smax[4];
    const int wave = tid >> 6, lane = tid & 63;
    if (lane == 0) smax[wave] = vmax;
    __syncthreads();
    if (tid == 0) {
        float m = fmaxf(fmaxf(smax[0], smax[1]), fmaxf(smax[2], smax[3]));
        atomicMax(&hdr[mat], __float_as_uint(m));  // positive floats: bit order == value order
    }
}

// ---------------------------------------------------------------------------
// Pass 2: histogram all |elem| >= 0.5*max directly (LDS hist -> sparse global
// merge). Bin = (float_bits - bits(0.5*max)) >> 13, clamped to NBINS-1: 2^-10
// relative bin width over [0.5*max, max].
// ---------------------------------------------------------------------------
__global__ __launch_bounds__(256) void k_pass_hist(
    const float* __restrict__ wa1, const float* __restrict__ wb1,
    const float* __restrict__ wa2, const float* __restrict__ wb2,
    const unsigned* __restrict__ hdr,
    unsigned* __restrict__ gcnt, float* __restrict__ gsum) {
    __shared__ unsigned lcnt[NBINS];
    __shared__ float lsum[NBINS];
    const int tid = threadIdx.x;
    const int mat = blockIdx.y;
    for (int b = tid; b < NBINS; b += 256) { lcnt[b] = 0u; lsum[b] = 0.f; }
    __syncthreads();

    const float* __restrict__ wa = mat ? wa2 : wa1;
    const float* __restrict__ wb = mat ? wb2 : wb1;
    const float T = 0.5f * __uint_as_float(hdr[mat]);
    const unsigned bitsT = __float_as_uint(T);
    const int i0 = (blockIdx.x & 3) * 1024 + tid * 4;
    const int obase = (blockIdx.x >> 2) * 64;

    float4 wbv[RANK];
#pragma unroll
    for (int r = 0; r < RANK; ++r)
        wbv[r] = *(const float4*)(wb + r * D + i0);

#pragma unroll 2
    for (int oo = 0; oo < 64; ++oo) {
        const float* __restrict__ war = wa + (size_t)(obase + oo) * RANK;
        float4 s = make_float4(0.f, 0.f, 0.f, 0.f);
#pragma unroll
        for (int r = 0; r < RANK; ++r) {
            const float a = war[r];
            s.x = fmaf(a, wbv[r].x, s.x);
            s.y = fmaf(a, wbv[r].y, s.y);
            s.z = fmaf(a, wbv[r].z, s.z);
            s.w = fmaf(a, wbv[r].w, s.w);
        }
        const float av[4] = {fabsf(s.x), fabsf(s.y), fabsf(s.z), fabsf(s.w)};
#pragma unroll
        for (int j = 0; j < 4; ++j) {
            if (av[j] >= T) {
                unsigned k = (__float_as_uint(av[j]) - bitsT) >> 13;
                if (k > NBINS - 1u) k = NBINS - 1u;
                atomicAdd(&lcnt[k], 1u);
                atomicAdd(&lsum[k], av[j]);
            }
        }
    }
    __syncthreads();
    unsigned* __restrict__ gc = gcnt + (size_t)mat * NBINS;
    float* __restrict__ gs = gsum + (size_t)mat * NBINS;
    for (int b = tid; b < NBINS; b += 256) {
        unsigned c = lcnt[b];
        if (c) {
            atomicAdd(&gc[b], c);
            atomicAdd(&gs[b], lsum[b]);
        }
    }
}

// ---------------------------------------------------------------------------
// Pass 3: one block, 1024 threads. Parallel suffix-scan of the histogram,
// locate the top-64 cutoff bin, compute flag.
// ---------------------------------------------------------------------------
__global__ __launch_bounds__(1024) void k_select(
    unsigned* __restrict__ hdr,
    const unsigned* __restrict__ gcnt, const float* __restrict__ gsum,
    const int* __restrict__ tsp) {
    __shared__ unsigned sc[NBINS];
    __shared__ float ss[NBINS];
    __shared__ float res[2];
    __shared__ int sB;
    const int b = threadIdx.x;

    for (int mat = 0; mat < 2; ++mat) {
        if (b == 0) sB = -1;
        const unsigned c0 = gcnt[(size_t)mat * NBINS + b];
        const float s0 = gsum[(size_t)mat * NBINS + b];
        __syncthreads();           // previous iteration's readers done
        sc[b] = c0;
        ss[b] = s0;
        __syncthreads();
        // Hillis-Steele suffix scan: sc[b] = sum_{b'>=b} cnt, ss likewise
        for (int step = 1; step < NBINS; step <<= 1) {
            unsigned c2 = 0u; float s2 = 0.f;
            if (b + step < NBINS) { c2 = sc[b + step]; s2 = ss[b + step]; }
            __syncthreads();
            sc[b] += c2;
            ss[b] += s2;
            __syncthreads();
        }
        // unique b with C(b) >= K_TOP > C(b+1)
        if (sc[b] >= K_TOP && (b == NBINS - 1 || sc[b + 1] < K_TOP)) sB = b;
        __syncthreads();
        if (b == 0) {
            float total;
            if (sB < 0) {
                total = ss[0];  // fewer than K_TOP candidates (won't happen at 0.5*max)
            } else {
                const int B = sB;
                const unsigned cAbove = (B + 1 < NBINS) ? sc[B + 1] : 0u;
                const float sAbove = (B + 1 < NBINS) ? ss[B + 1] : 0.f;
                const unsigned cb = sc[B] - cAbove;
                const float sb = ss[B] - sAbove;
                const unsigned need = K_TOP - cAbove;
                total = sAbove + sb * ((float)need / (float)cb);  // bin-avg approx, 2^-10 rel
            }
            res[mat] = total;
        }
        __syncthreads();
    }
    if (b == 0) {
        const int tr = (*tsp) % SUM_TIMESTEPS;
        const float scale = fmodf(ALPHA * (float)tr / (float)SUM_TIMESTEPS + BETA, ALPHA);
        const float temp_ratio = res[0] / (res[1] * scale);  // AVG_RATIO = 1.0
        hdr[4] = (temp_ratio > 1.0f) ? 1u : 0u;              // 1 -> matrix1
    }
}

// ---------------------------------------------------------------------------
// Kernel T: t[m, r] = sum_i h[m,i] * wb[r,i].  Streams h (128 MiB).
// Block = 4 waves; each wave owns 4 rows (halves redundant wb L2 traffic
// vs 2 rows); lane owns 4 i's per k-slice.
// ---------------------------------------------------------------------------
__global__ __launch_bounds__(256) void k_t(
    const float* __restrict__ h, const float* __restrict__ wb1,
    const float* __restrict__ wb2, const unsigned* __restrict__ hdr,
    float* __restrict__ t) {
    const int tid = threadIdx.x;
    const int wave = tid >> 6, lane = tid & 63;
    const float* __restrict__ wb = hdr[4] ? wb1 : wb2;
    const int m0 = blockIdx.x * 16 + wave * 4;

    float acc[4][RANK];
#pragma unroll
    for (int row = 0; row < 4; ++row)
#pragma unroll
        for (int r = 0; r < RANK; ++r) acc[row][r] = 0.f;

    for (int k = 0; k < 16; ++k) {
        const int i = k * 256 + lane * 4;
        float4 wbv[RANK];
#pragma unroll
        for (int r = 0; r < RANK; ++r)
            wbv[r] = *(const float4*)(wb + r * D + i);
#pragma unroll
        for (int row = 0; row < 4; ++row) {
            const float4 hv = *(const float4*)(h + (size_t)(m0 + row) * D + i);
#pragma unroll
            for (int r = 0; r < RANK; ++r)
                acc[row][r] = fmaf(hv.x, wbv[r].x,
                              fmaf(hv.y, wbv[r].y,
                              fmaf(hv.z, wbv[r].z,
                              fmaf(hv.w, wbv[r].w, acc[row][r]))));
        }
    }
#pragma unroll
    for (int row = 0; row < 4; ++row)
#pragma unroll
        for (int r = 0; r < RANK; ++r)
            for (int off = 32; off; off >>= 1)
                acc[row][r] += __shfl_xor(acc[row][r], off, 64);
    if (lane == 0) {
#pragma unroll
        for (int row = 0; row < 4; ++row)
#pragma unroll
            for (int r = 0; r < RANK; ++r)
                t[(size_t)(m0 + row) * RANK + r] = acc[row][r];
    }
}

// ---------------------------------------------------------------------------
// Kernel O: out[m, o] = sum_r t[m,r] * wa[o,r].  Streams out (128 MiB).
// ---------------------------------------------------------------------------
__global__ __launch_bounds__(256) void k_o(
    const float* __restrict__ t, const float* __restrict__ wa1,
    const float* __restrict__ wa2, const unsigned* __restrict__ hdr,
    float* __restrict__ out) {
    const int tid = threadIdx.x;
    const float* __restrict__ wa = hdr[4] ? wa1 : wa2;
    const int o0 = (blockIdx.x & 3) * 1024 + tid * 4;
    const int m0 = (blockIdx.x >> 2) * 16;

    float4 A[8];  // A[2j+0]: (o0+j) r0..3, A[2j+1]: (o0+j) r4..7
#pragma unroll
    for (int j = 0; j < 8; ++j)
        A[j] = *(const float4*)(wa + (size_t)o0 * RANK + j * 4);

    for (int rr = 0; rr < 16; ++rr) {
        const int m = m0 + rr;
        const float4 t03 = *(const float4*)(t + (size_t)m * RANK);
        const float4 t47 = *(const float4*)(t + (size_t)m * RANK + 4);
        float4 ov;
        ov.x = dot4(A[0], t03) + dot4(A[1], t47);
        ov.y = dot4(A[2], t03) + dot4(A[3], t47);
        ov.z = dot4(A[4], t03) + dot4(A[5], t47);
        ov.w = dot4(A[6], t03) + dot4(A[7], t47);
        *(float4*)(out + (size_t)m * D + o0) = ov;
    }
}

extern "C" void kernel_launch(void* const* d_in, const int* in_sizes, int n_in,
                              void* d_out, int out_size, void* d_ws, size_t ws_size,
                              hipStream_t stream) {
    const float* h   = (const float*)d_in[0];
    const float* wa1 = (const float*)d_in[1];
    const float* wb1 = (const float*)d_in[2];
    const float* wa2 = (const float*)d_in[3];
    const float* wb2 = (const float*)d_in[4];
    const int*   ts  = (const int*)d_in[5];
    float* out = (float*)d_out;

    const int rows = in_sizes[0] / D;  // 8192

    unsigned* hdr  = (unsigned*)d_ws;
    unsigned* gcnt = (unsigned*)((char*)d_ws + WS_HCNT_OFF);
    float*    gsum = (float*)((char*)d_ws + WS_HSUM_OFF);
    float*    tbuf = (float*)((char*)d_ws + WS_T_OFF);

    hipLaunchKernelGGL(k_init, dim3(1), dim3(1024), 0, stream, (unsigned*)d_ws);
    hipLaunchKernelGGL(k_pass_max, dim3(256, 2), dim3(256), 0, stream,
                       wa1, wb1, wa2, wb2, hdr);
    hipLaunchKernelGGL(k_pass_hist, dim3(256, 2), dim3(256), 0, stream,
                       wa1, wb1, wa2, wb2, hdr, gcnt, gsum);
    hipLaunchKernelGGL(k_select, dim3(1), dim3(1024), 0, stream,
                       hdr, gcnt, gsum, ts);
    hipLaunchKernelGGL(k_t, dim3(rows / 16), dim3(256), 0, stream,
                       h, wb1, wb2, hdr, tbuf);
    hipLaunchKernelGGL(k_o, dim3(4 * (rows / 16)), dim3(256), 0, stream,
                       tbuf, wa1, wa2, hdr, out);
}

// Round 3
// 121.634 us; speedup vs baseline: 1.9797x; 1.1405x over previous
//
#include <hip/hip_runtime.h>
#include <stdint.h>

#define D 4096
#define RANK 8
#define ALPHA 1.5f
#define BETA 0.5f
#define SUM_TIMESTEPS 28000
#define K_TOP 64
#define NBINS 1024
#define M_BLK 8

// ws layout (bytes):
//   [0, 256)        : u32 hdr[]: [0]=maxbits1 [1]=maxbits2 [4]=flag
//   [256, 256+8K)   : u32  gcnt[2][NBINS]
//   [256+8K, +16K)  : f32  gsum[2][NBINS]
#define WS_HCNT_OFF 256
#define WS_HSUM_OFF (256 + 2 * NBINS * 4)

__global__ __launch_bounds__(1024) void k_init(unsigned* __restrict__ w) {
    // zero hdr + both histograms: (256 + 16384)/4 = 4160 words
    for (int i = threadIdx.x; i < 4160; i += 1024) w[i] = 0u;
}

__device__ __forceinline__ float dot4(float4 a, float4 b) {
    return fmaf(a.x, b.x, fmaf(a.y, b.y, fmaf(a.z, b.z, a.w * b.w)));
}

// ---------------------------------------------------------------------------
// Pass 1: global max of |wa@wb| per matrix.
// grid: (4 i-tiles * 64 o-chunks, 2 matrices), block 256.
// ---------------------------------------------------------------------------
__global__ __launch_bounds__(256) void k_pass_max(
    const float* __restrict__ wa1, const float* __restrict__ wb1,
    const float* __restrict__ wa2, const float* __restrict__ wb2,
    unsigned* __restrict__ hdr) {
    const int tid = threadIdx.x;
    const int mat = blockIdx.y;
    const float* __restrict__ wa = mat ? wa2 : wa1;
    const float* __restrict__ wb = mat ? wb2 : wb1;
    const int i0 = (blockIdx.x & 3) * 1024 + tid * 4;
    const int obase = (blockIdx.x >> 2) * 64;

    float4 wbv[RANK];
#pragma unroll
    for (int r = 0; r < RANK; ++r)
        wbv[r] = *(const float4*)(wb + r * D + i0);

    float vmax = 0.f;
#pragma unroll 4
    for (int oo = 0; oo < 64; ++oo) {
        const float* __restrict__ war = wa + (size_t)(obase + oo) * RANK;
        float4 s = make_float4(0.f, 0.f, 0.f, 0.f);
#pragma unroll
        for (int r = 0; r < RANK; ++r) {
            const float a = war[r];
            s.x = fmaf(a, wbv[r].x, s.x);
            s.y = fmaf(a, wbv[r].y, s.y);
            s.z = fmaf(a, wbv[r].z, s.z);
            s.w = fmaf(a, wbv[r].w, s.w);
        }
        vmax = fmaxf(vmax, fmaxf(fmaxf(fabsf(s.x), fabsf(s.y)),
                                 fmaxf(fabsf(s.z), fabsf(s.w))));
    }
    for (int off = 32; off; off >>= 1)
        vmax = fmaxf(vmax, __shfl_xor(vmax, off, 64));
    __shared__ float smax[4];
    const int wave = tid >> 6, lane = tid & 63;
    if (lane == 0) smax[wave] = vmax;
    __syncthreads();
    if (tid == 0) {
        float m = fmaxf(fmaxf(smax[0], smax[1]), fmaxf(smax[2], smax[3]));
        atomicMax(&hdr[mat], __float_as_uint(m));  // positive floats: bit order == value order
    }
}

// ---------------------------------------------------------------------------
// Pass 2: histogram all |elem| >= 0.5*max (LDS hist -> sparse global merge).
// Bin = (float_bits - bits(0.5*max)) >> 13, clamp NBINS-1: exactly one octave,
// 2^-10 relative bin width.
// ---------------------------------------------------------------------------
__global__ __launch_bounds__(256) void k_pass_hist(
    const float* __restrict__ wa1, const float* __restrict__ wb1,
    const float* __restrict__ wa2, const float* __restrict__ wb2,
    const unsigned* __restrict__ hdr,
    unsigned* __restrict__ gcnt, float* __restrict__ gsum) {
    __shared__ unsigned lcnt[NBINS];
    __shared__ float lsum[NBINS];
    const int tid = threadIdx.x;
    const int mat = blockIdx.y;
    for (int b = tid; b < NBINS; b += 256) { lcnt[b] = 0u; lsum[b] = 0.f; }
    __syncthreads();

    const float* __restrict__ wa = mat ? wa2 : wa1;
    const float* __restrict__ wb = mat ? wb2 : wb1;
    const float T = 0.5f * __uint_as_float(hdr[mat]);
    const unsigned bitsT = __float_as_uint(T);
    const int i0 = (blockIdx.x & 3) * 1024 + tid * 4;
    const int obase = (blockIdx.x >> 2) * 64;

    float4 wbv[RANK];
#pragma unroll
    for (int r = 0; r < RANK; ++r)
        wbv[r] = *(const float4*)(wb + r * D + i0);

#pragma unroll 2
    for (int oo = 0; oo < 64; ++oo) {
        const float* __restrict__ war = wa + (size_t)(obase + oo) * RANK;
        float4 s = make_float4(0.f, 0.f, 0.f, 0.f);
#pragma unroll
        for (int r = 0; r < RANK; ++r) {
            const float a = war[r];
            s.x = fmaf(a, wbv[r].x, s.x);
            s.y = fmaf(a, wbv[r].y, s.y);
            s.z = fmaf(a, wbv[r].z, s.z);
            s.w = fmaf(a, wbv[r].w, s.w);
        }
        const float av[4] = {fabsf(s.x), fabsf(s.y), fabsf(s.z), fabsf(s.w)};
#pragma unroll
        for (int j = 0; j < 4; ++j) {
            if (av[j] >= T) {
                unsigned k = (__float_as_uint(av[j]) - bitsT) >> 13;
                if (k > NBINS - 1u) k = NBINS - 1u;
                atomicAdd(&lcnt[k], 1u);
                atomicAdd(&lsum[k], av[j]);
            }
        }
    }
    __syncthreads();
    unsigned* __restrict__ gc = gcnt + (size_t)mat * NBINS;
    float* __restrict__ gs = gsum + (size_t)mat * NBINS;
    for (int b = tid; b < NBINS; b += 256) {
        unsigned c = lcnt[b];
        if (c) {
            atomicAdd(&gc[b], c);
            atomicAdd(&gs[b], lsum[b]);
        }
    }
}

// ---------------------------------------------------------------------------
// Pass 3: one block, 1024 threads. Parallel suffix-scan of histogram, locate
// the top-64 cutoff bin, compute flag.
// ---------------------------------------------------------------------------
__global__ __launch_bounds__(1024) void k_select(
    unsigned* __restrict__ hdr,
    const unsigned* __restrict__ gcnt, const float* __restrict__ gsum,
    const int* __restrict__ tsp) {
    __shared__ unsigned sc[NBINS];
    __shared__ float ss[NBINS];
    __shared__ float res[2];
    __shared__ int sB;
    const int b = threadIdx.x;

    for (int mat = 0; mat < 2; ++mat) {
        if (b == 0) sB = -1;
        const unsigned c0 = gcnt[(size_t)mat * NBINS + b];
        const float s0 = gsum[(size_t)mat * NBINS + b];
        __syncthreads();           // previous iteration's readers done
        sc[b] = c0;
        ss[b] = s0;
        __syncthreads();
        // Hillis-Steele suffix scan: sc[b] = sum_{b'>=b} cnt, ss likewise
        for (int step = 1; step < NBINS; step <<= 1) {
            unsigned c2 = 0u; float s2 = 0.f;
            if (b + step < NBINS) { c2 = sc[b + step]; s2 = ss[b + step]; }
            __syncthreads();
            sc[b] += c2;
            ss[b] += s2;
            __syncthreads();
        }
        if (sc[b] >= K_TOP && (b == NBINS - 1 || sc[b + 1] < K_TOP)) sB = b;
        __syncthreads();
        if (b == 0) {
            float total;
            if (sB < 0) {
                total = ss[0];
            } else {
                const int B = sB;
                const unsigned cAbove = (B + 1 < NBINS) ? sc[B + 1] : 0u;
                const float sAbove = (B + 1 < NBINS) ? ss[B + 1] : 0.f;
                const unsigned cb = sc[B] - cAbove;
                const float sb = ss[B] - sAbove;
                const unsigned need = K_TOP - cAbove;
                total = sAbove + sb * ((float)need / (float)cb);  // bin-avg approx, 2^-10 rel
            }
            res[mat] = total;
        }
        __syncthreads();
    }
    if (b == 0) {
        const int tr = (*tsp) % SUM_TIMESTEPS;
        const float scale = fmodf(ALPHA * (float)tr / (float)SUM_TIMESTEPS + BETA, ALPHA);
        const float temp_ratio = res[0] / (res[1] * scale);  // AVG_RATIO = 1.0
        hdr[4] = (temp_ratio > 1.0f) ? 1u : 0u;              // 1 -> matrix1
    }
}

// ---------------------------------------------------------------------------
// Fused GEMM: per block of M_BLK=8 rows:
//   phase 1: t[8][8] = h_rows @ wb^T (wave owns 2 rows, shuffle-reduce -> LDS)
//   phase 2: out_rows = t @ wa^T (thread owns 4 o-cols/chunk, 4 chunks)
// Streams h in (128 KiB/block) and out (128 KiB/block); wa/wb stay L2-hot.
// ---------------------------------------------------------------------------
__global__ __launch_bounds__(256) void k_fused(
    const float* __restrict__ h,
    const float* __restrict__ wa1, const float* __restrict__ wb1,
    const float* __restrict__ wa2, const float* __restrict__ wb2,
    const unsigned* __restrict__ hdr,
    float* __restrict__ out) {
    const int tid = threadIdx.x;
    const int wave = tid >> 6, lane = tid & 63;
    const unsigned flag = hdr[4];
    const float* __restrict__ wa = flag ? wa1 : wa2;
    const float* __restrict__ wb = flag ? wb1 : wb2;
    const size_t m0 = (size_t)blockIdx.x * M_BLK;
    __shared__ float t_s[M_BLK][RANK];

    // ---- phase 1: rows m0 + 2*wave + {0,1} ----
    const int mrow = wave * 2;
    float acc[2][RANK];
#pragma unroll
    for (int row = 0; row < 2; ++row)
#pragma unroll
        for (int r = 0; r < RANK; ++r) acc[row][r] = 0.f;

#pragma unroll 4
    for (int k = 0; k < 16; ++k) {
        const int i = k * 256 + lane * 4;
        float4 wbv[RANK];
#pragma unroll
        for (int r = 0; r < RANK; ++r)
            wbv[r] = *(const float4*)(wb + r * D + i);
#pragma unroll
        for (int row = 0; row < 2; ++row) {
            const float4 hv = *(const float4*)(h + (m0 + mrow + row) * D + i);
#pragma unroll
            for (int r = 0; r < RANK; ++r)
                acc[row][r] = fmaf(hv.x, wbv[r].x,
                              fmaf(hv.y, wbv[r].y,
                              fmaf(hv.z, wbv[r].z,
                              fmaf(hv.w, wbv[r].w, acc[row][r]))));
        }
    }
#pragma unroll
    for (int row = 0; row < 2; ++row)
#pragma unroll
        for (int r = 0; r < RANK; ++r)
            for (int off = 32; off; off >>= 1)
                acc[row][r] += __shfl_xor(acc[row][r], off, 64);
    if (lane == 0) {
#pragma unroll
        for (int row = 0; row < 2; ++row)
#pragma unroll
            for (int r = 0; r < RANK; ++r)
                t_s[mrow + row][r] = acc[row][r];
    }
    __syncthreads();

    // ---- phase 2: out[m0..m0+7, :] = t_s @ wa^T ----
#pragma unroll
    for (int c = 0; c < 4; ++c) {
        const int o0 = c * 1024 + tid * 4;
        float4 A[8];  // A[2j+0]: col (o0+j) r0..3, A[2j+1]: r4..7 (contiguous 128 B)
#pragma unroll
        for (int j = 0; j < 8; ++j)
            A[j] = *(const float4*)(wa + (size_t)o0 * RANK + j * 4);
#pragma unroll
        for (int rr = 0; rr < M_BLK; ++rr) {
            const float4 t03 = *(const float4*)&t_s[rr][0];
            const float4 t47 = *(const float4*)&t_s[rr][4];
            float4 ov;
            ov.x = dot4(A[0], t03) + dot4(A[1], t47);
            ov.y = dot4(A[2], t03) + dot4(A[3], t47);
            ov.z = dot4(A[4], t03) + dot4(A[5], t47);
            ov.w = dot4(A[6], t03) + dot4(A[7], t47);
            *(float4*)(out + (m0 + rr) * D + o0) = ov;
        }
    }
}

extern "C" void kernel_launch(void* const* d_in, const int* in_sizes, int n_in,
                              void* d_out, int out_size, void* d_ws, size_t ws_size,
                              hipStream_t stream) {
    const float* h   = (const float*)d_in[0];
    const float* wa1 = (const float*)d_in[1];
    const float* wb1 = (const float*)d_in[2];
    const float* wa2 = (const float*)d_in[3];
    const float* wb2 = (const float*)d_in[4];
    const int*   ts  = (const int*)d_in[5];
    float* out = (float*)d_out;

    const int rows = in_sizes[0] / D;  // 8192

    unsigned* hdr  = (unsigned*)d_ws;
    unsigned* gcnt = (unsigned*)((char*)d_ws + WS_HCNT_OFF);
    float*    gsum = (float*)((char*)d_ws + WS_HSUM_OFF);

    hipLaunchKernelGGL(k_init, dim3(1), dim3(1024), 0, stream, (unsigned*)d_ws);
    hipLaunchKernelGGL(k_pass_max, dim3(256, 2), dim3(256), 0, stream,
                       wa1, wb1, wa2, wb2, hdr);
    hipLaunchKernelGGL(k_pass_hist, dim3(256, 2), dim3(256), 0, stream,
                       wa1, wb1, wa2, wb2, hdr, gcnt, gsum);
    hipLaunchKernelGGL(k_select, dim3(1), dim3(1024), 0, stream,
                       hdr, gcnt, gsum, ts);
    hipLaunchKernelGGL(k_fused, dim3(rows / M_BLK), dim3(256), 0, stream,
                       h, wa1, wb1, wa2, wb2, hdr, out);
}

// Round 4
// 118.843 us; speedup vs baseline: 2.0262x; 1.0235x over previous
//
#include <hip/hip_runtime.h>
#include <stdint.h>

#define D 4096
#define RANK 8
#define ALPHA 1.5f
#define BETA 0.5f
#define SUM_TIMESTEPS 28000
#define K_TOP 64
#define NBINS 1024

typedef float f32x4 __attribute__((ext_vector_type(4)));

// ws layout (bytes):
//   [0, 256)        : u32 hdr[]: [0]=maxbits1 [1]=maxbits2 [4]=flag
//   [256, 256+8K)   : u32  gcnt[2][NBINS]
//   [256+8K, +16K)  : f32  gsum[2][NBINS]
#define WS_HCNT_OFF 256
#define WS_HSUM_OFF (256 + 2 * NBINS * 4)

__global__ __launch_bounds__(1024) void k_init(unsigned* __restrict__ w) {
    for (int i = threadIdx.x; i < 4160; i += 1024) w[i] = 0u;
}

__device__ __forceinline__ float dot8(f32x4 a0, f32x4 a1, const float* t) {
    return fmaf(a0.x, t[0], fmaf(a0.y, t[1], fmaf(a0.z, t[2], fmaf(a0.w, t[3],
           fmaf(a1.x, t[4], fmaf(a1.y, t[5], fmaf(a1.z, t[6], a1.w * t[7])))))));
}

// ---------------------------------------------------------------------------
// Pass 1: global max of |wa@wb| per matrix.
// ---------------------------------------------------------------------------
__global__ __launch_bounds__(256) void k_pass_max(
    const float* __restrict__ wa1, const float* __restrict__ wb1,
    const float* __restrict__ wa2, const float* __restrict__ wb2,
    unsigned* __restrict__ hdr) {
    const int tid = threadIdx.x;
    const int mat = blockIdx.y;
    const float* __restrict__ wa = mat ? wa2 : wa1;
    const float* __restrict__ wb = mat ? wb2 : wb1;
    const int i0 = (blockIdx.x & 3) * 1024 + tid * 4;
    const int obase = (blockIdx.x >> 2) * 64;

    f32x4 wbv[RANK];
#pragma unroll
    for (int r = 0; r < RANK; ++r)
        wbv[r] = *(const f32x4*)(wb + r * D + i0);

    float vmax = 0.f;
#pragma unroll 4
    for (int oo = 0; oo < 64; ++oo) {
        const float* __restrict__ war = wa + (size_t)(obase + oo) * RANK;
        f32x4 s = {0.f, 0.f, 0.f, 0.f};
#pragma unroll
        for (int r = 0; r < RANK; ++r) {
            const float a = war[r];
            s.x = fmaf(a, wbv[r].x, s.x);
            s.y = fmaf(a, wbv[r].y, s.y);
            s.z = fmaf(a, wbv[r].z, s.z);
            s.w = fmaf(a, wbv[r].w, s.w);
        }
        vmax = fmaxf(vmax, fmaxf(fmaxf(fabsf(s.x), fabsf(s.y)),
                                 fmaxf(fabsf(s.z), fabsf(s.w))));
    }
    for (int off = 32; off; off >>= 1)
        vmax = fmaxf(vmax, __shfl_xor(vmax, off, 64));
    __shared__ float smax[4];
    const int wave = tid >> 6, lane = tid & 63;
    if (lane == 0) smax[wave] = vmax;
    __syncthreads();
    if (tid == 0) {
        float m = fmaxf(fmaxf(smax[0], smax[1]), fmaxf(smax[2], smax[3]));
        atomicMax(&hdr[mat], __float_as_uint(m));  // positive floats: bit order == value order
    }
}

// ---------------------------------------------------------------------------
// Pass 2: histogram all |elem| >= 0.5*max (LDS hist -> sparse global merge).
// ---------------------------------------------------------------------------
__global__ __launch_bounds__(256) void k_pass_hist(
    const float* __restrict__ wa1, const float* __restrict__ wb1,
    const float* __restrict__ wa2, const float* __restrict__ wb2,
    const unsigned* __restrict__ hdr,
    unsigned* __restrict__ gcnt, float* __restrict__ gsum) {
    __shared__ unsigned lcnt[NBINS];
    __shared__ float lsum[NBINS];
    const int tid = threadIdx.x;
    const int mat = blockIdx.y;
    for (int b = tid; b < NBINS; b += 256) { lcnt[b] = 0u; lsum[b] = 0.f; }
    __syncthreads();

    const float* __restrict__ wa = mat ? wa2 : wa1;
    const float* __restrict__ wb = mat ? wb2 : wb1;
    const float T = 0.5f * __uint_as_float(hdr[mat]);
    const unsigned bitsT = __float_as_uint(T);
    const int i0 = (blockIdx.x & 3) * 1024 + tid * 4;
    const int obase = (blockIdx.x >> 2) * 64;

    f32x4 wbv[RANK];
#pragma unroll
    for (int r = 0; r < RANK; ++r)
        wbv[r] = *(const f32x4*)(wb + r * D + i0);

#pragma unroll 2
    for (int oo = 0; oo < 64; ++oo) {
        const float* __restrict__ war = wa + (size_t)(obase + oo) * RANK;
        f32x4 s = {0.f, 0.f, 0.f, 0.f};
#pragma unroll
        for (int r = 0; r < RANK; ++r) {
            const float a = war[r];
            s.x = fmaf(a, wbv[r].x, s.x);
            s.y = fmaf(a, wbv[r].y, s.y);
            s.z = fmaf(a, wbv[r].z, s.z);
            s.w = fmaf(a, wbv[r].w, s.w);
        }
        const float av[4] = {fabsf(s.x), fabsf(s.y), fabsf(s.z), fabsf(s.w)};
#pragma unroll
        for (int j = 0; j < 4; ++j) {
            if (av[j] >= T) {
                unsigned k = (__float_as_uint(av[j]) - bitsT) >> 13;
                if (k > NBINS - 1u) k = NBINS - 1u;
                atomicAdd(&lcnt[k], 1u);
                atomicAdd(&lsum[k], av[j]);
            }
        }
    }
    __syncthreads();
    unsigned* __restrict__ gc = gcnt + (size_t)mat * NBINS;
    float* __restrict__ gs = gsum + (size_t)mat * NBINS;
    for (int b = tid; b < NBINS; b += 256) {
        unsigned c = lcnt[b];
        if (c) {
            atomicAdd(&gc[b], c);
            atomicAdd(&gs[b], lsum[b]);
        }
    }
}

// ---------------------------------------------------------------------------
// Pass 3: one block, 1024 threads; suffix-scan histogram, top-64 cutoff, flag.
// ---------------------------------------------------------------------------
__global__ __launch_bounds__(1024) void k_select(
    unsigned* __restrict__ hdr,
    const unsigned* __restrict__ gcnt, const float* __restrict__ gsum,
    const int* __restrict__ tsp) {
    __shared__ unsigned sc[NBINS];
    __shared__ float ss[NBINS];
    __shared__ float res[2];
    __shared__ int sB;
    const int b = threadIdx.x;

    for (int mat = 0; mat < 2; ++mat) {
        if (b == 0) sB = -1;
        const unsigned c0 = gcnt[(size_t)mat * NBINS + b];
        const float s0 = gsum[(size_t)mat * NBINS + b];
        __syncthreads();
        sc[b] = c0;
        ss[b] = s0;
        __syncthreads();
        for (int step = 1; step < NBINS; step <<= 1) {
            unsigned c2 = 0u; float s2 = 0.f;
            if (b + step < NBINS) { c2 = sc[b + step]; s2 = ss[b + step]; }
            __syncthreads();
            sc[b] += c2;
            ss[b] += s2;
            __syncthreads();
        }
        if (sc[b] >= K_TOP && (b == NBINS - 1 || sc[b + 1] < K_TOP)) sB = b;
        __syncthreads();
        if (b == 0) {
            float total;
            if (sB < 0) {
                total = ss[0];
            } else {
                const int B = sB;
                const unsigned cAbove = (B + 1 < NBINS) ? sc[B + 1] : 0u;
                const float sAbove = (B + 1 < NBINS) ? ss[B + 1] : 0.f;
                const unsigned cb = sc[B] - cAbove;
                const float sb = ss[B] - sAbove;
                const unsigned need = K_TOP - cAbove;
                total = sAbove + sb * ((float)need / (float)cb);
            }
            res[mat] = total;
        }
        __syncthreads();
    }
    if (b == 0) {
        const int tr = (*tsp) % SUM_TIMESTEPS;
        const float scale = fmodf(ALPHA * (float)tr / (float)SUM_TIMESTEPS + BETA, ALPHA);
        const float temp_ratio = res[0] / (res[1] * scale);  // AVG_RATIO = 1.0
        hdr[4] = (temp_ratio > 1.0f) ? 1u : 0u;              // 1 -> matrix1
    }
}

// ---------------------------------------------------------------------------
// Fused GEMM, wave-independent: each wave owns 4 rows end-to-end.
//   phase 1: acc[4][8] = h_rows @ wb^T; xor-butterfly leaves full t in EVERY
//            lane (no LDS, no barrier).
//   phase 2: the same wave streams its 4 output rows (nt stores).
// Waves desynchronize -> reads and writes interleave on the HBM bus.
// ---------------------------------------------------------------------------
__global__ __launch_bounds__(256) void k_fused(
    const float* __restrict__ h,
    const float* __restrict__ wa1, const float* __restrict__ wb1,
    const float* __restrict__ wa2, const float* __restrict__ wb2,
    const unsigned* __restrict__ hdr,
    float* __restrict__ out) {
    const int tid = threadIdx.x;
    const int wave = tid >> 6, lane = tid & 63;
    const unsigned flag = hdr[4];
    const float* __restrict__ wa = flag ? wa1 : wa2;
    const float* __restrict__ wb = flag ? wb1 : wb2;
    const size_t m0 = ((size_t)blockIdx.x * 4 + wave) * 4;

    float acc[4][RANK];
#pragma unroll
    for (int row = 0; row < 4; ++row)
#pragma unroll
        for (int r = 0; r < RANK; ++r) acc[row][r] = 0.f;

#pragma unroll 4
    for (int k = 0; k < 16; ++k) {
        const int i = k * 256 + lane * 4;
        f32x4 hv[4];
#pragma unroll
        for (int row = 0; row < 4; ++row)
            hv[row] = *(const f32x4*)(h + (m0 + row) * D + i);
        f32x4 wbv[RANK];
#pragma unroll
        for (int r = 0; r < RANK; ++r)
            wbv[r] = *(const f32x4*)(wb + r * D + i);
#pragma unroll
        for (int row = 0; row < 4; ++row)
#pragma unroll
            for (int r = 0; r < RANK; ++r)
                acc[row][r] = fmaf(hv[row].x, wbv[r].x,
                              fmaf(hv[row].y, wbv[r].y,
                              fmaf(hv[row].z, wbv[r].z,
                              fmaf(hv[row].w, wbv[r].w, acc[row][r]))));
    }
    // butterfly reduce over i: afterwards every lane holds t[row][r]
#pragma unroll
    for (int row = 0; row < 4; ++row)
#pragma unroll
        for (int r = 0; r < RANK; ++r)
#pragma unroll
            for (int off = 32; off; off >>= 1)
                acc[row][r] += __shfl_xor(acc[row][r], off, 64);

    // phase 2: out[m0..m0+3, :] = t @ wa^T, 256 cols per chunk
    for (int c = 0; c < 16; ++c) {
        const int o0 = c * 256 + lane * 4;
        f32x4 A[8];  // A[2j]: col (o0+j) r0..3, A[2j+1]: r4..7
#pragma unroll
        for (int j = 0; j < 8; ++j)
            A[j] = *(const f32x4*)(wa + (size_t)o0 * RANK + j * 4);
#pragma unroll
        for (int row = 0; row < 4; ++row) {
            f32x4 ov;
            ov.x = dot8(A[0], A[1], acc[row]);
            ov.y = dot8(A[2], A[3], acc[row]);
            ov.z = dot8(A[4], A[5], acc[row]);
            ov.w = dot8(A[6], A[7], acc[row]);
            __builtin_nontemporal_store(ov, (f32x4*)(out + (m0 + row) * D + o0));
        }
    }
}

extern "C" void kernel_launch(void* const* d_in, const int* in_sizes, int n_in,
                              void* d_out, int out_size, void* d_ws, size_t ws_size,
                              hipStream_t stream) {
    const float* h   = (const float*)d_in[0];
    const float* wa1 = (const float*)d_in[1];
    const float* wb1 = (const float*)d_in[2];
    const float* wa2 = (const float*)d_in[3];
    const float* wb2 = (const float*)d_in[4];
    const int*   ts  = (const int*)d_in[5];
    float* out = (float*)d_out;

    const int rows = in_sizes[0] / D;  // 8192

    unsigned* hdr  = (unsigned*)d_ws;
    unsigned* gcnt = (unsigned*)((char*)d_ws + WS_HCNT_OFF);
    float*    gsum = (float*)((char*)d_ws + WS_HSUM_OFF);

    hipLaunchKernelGGL(k_init, dim3(1), dim3(1024), 0, stream, (unsigned*)d_ws);
    hipLaunchKernelGGL(k_pass_max, dim3(256, 2), dim3(256), 0, stream,
                       wa1, wb1, wa2, wb2, hdr);
    hipLaunchKernelGGL(k_pass_hist, dim3(256, 2), dim3(256), 0, stream,
                       wa1, wb1, wa2, wb2, hdr, gcnt, gsum);
    hipLaunchKernelGGL(k_select, dim3(1), dim3(1024), 0, stream,
                       hdr, gcnt, gsum, ts);
    hipLaunchKernelGGL(k_fused, dim3(rows / 16), dim3(256), 0, stream,
                       h, wa1, wb1, wa2, wb2, hdr, out);
}